// Round 22
// baseline (699.414 us; speedup 1.0000x reference)
//
#include <hip/hip_runtime.h>
#include <math.h>

// ---------------- constants ----------------
constexpr int DM = 512, DS = 16, DC = 4, DI = 1024, DI4 = 256, KC = 5;
constexpr int Bb = 4, N = 1024, L4 = 4, TT = Bb * N, TT2 = 2 * TT;
constexpr float TEMP = 0.5f;
constexpr int SEG = 16;          // scan segments per sequence (R20: 32 regressed; 16 is optimal)
constexpr int SLEN = N / SEG;    // 64 tokens per segment
constexpr int SEGU = 64;         // kmeans-update segments
constexpr float LOG2E = 1.44269504f;

typedef __attribute__((ext_vector_type(8))) short short8v;
typedef __attribute__((ext_vector_type(4))) float float4v;

__device__ inline ushort f2bf(float f) {
    union { float f; unsigned u; } v; v.f = f;
    unsigned r = v.u + 0x7FFFu + ((v.u >> 16) & 1u);
    return (ushort)(r >> 16);
}
__device__ inline float bf2f(ushort u) {
    union { unsigned u; float f; } v; v.u = ((unsigned)u) << 16;
    return v.f;
}
__device__ inline void gld16(const void* g, void* lds) {
    __builtin_amdgcn_global_load_lds(
        (const __attribute__((address_space(1))) unsigned int*)g,
        (__attribute__((address_space(3))) unsigned int*)lds, 16, 0, 0);
}
// hardware exp2 (single v_exp_f32)
__device__ inline float hexp2(float x) { return __builtin_amdgcn_exp2f(x); }
// fast sigmoid: v_rcp_f32 approx (rel err ~1e-5, << bf16 rounding)
__device__ inline float sigm(float x) {
    return __builtin_amdgcn_rcpf(1.f + __expf(-x));
}
// fast softplus: hw log/exp
__device__ inline float softp(float a) {
    return (a > 20.f) ? a : __logf(1.f + __expf(a));
}

// ---------------- k-means assign (wave-per-token, float4) ----------------
template <bool FINAL>
__global__ __launch_bounds__(256) void assign_k(const float* __restrict__ x,
                                                const float* __restrict__ cen0,
                                                int cbstride,
                                                float* __restrict__ wgt,
                                                float* __restrict__ mind,
                                                float* __restrict__ keys) {
    int t = blockIdx.x * 4 + (threadIdx.x >> 6);   // token
    int b = t >> 10;
    int lane = threadIdx.x & 63;
    const float4* xr = (const float4*)(x + (size_t)t * DM);
    float4 xv0 = xr[lane], xv1 = xr[lane + 64];
    const float* cenb = cen0 + (size_t)b * cbstride;
    float d2[KC];
#pragma unroll
    for (int k = 0; k < KC; ++k) {
        const float4* cr = (const float4*)(cenb + k * DM);
        float4 c0 = cr[lane], c1 = cr[lane + 64];
        float dx = xv0.x - c0.x, dy = xv0.y - c0.y, dz = xv0.z - c0.z, dw = xv0.w - c0.w;
        float acc = dx * dx + dy * dy + dz * dz + dw * dw;
        dx = xv1.x - c1.x; dy = xv1.y - c1.y; dz = xv1.z - c1.z; dw = xv1.w - c1.w;
        acc += dx * dx + dy * dy + dz * dz + dw * dw;
        d2[k] = acc;
    }
#pragma unroll
    for (int k = 0; k < KC; ++k)
        for (int off = 32; off > 0; off >>= 1) d2[k] += __shfl_xor(d2[k], off);
    if (lane == 0) {
        float dist[KC], logit[KC], e[KC];
        float lm = -1e30f;
        for (int k = 0; k < KC; ++k) {
            dist[k] = sqrtf(d2[k] + 1e-12f);
            logit[k] = -dist[k] / TEMP;
            lm = fmaxf(lm, logit[k]);
        }
        float s = 0.f;
        for (int k = 0; k < KC; ++k) { e[k] = expf(logit[k] - lm); s += e[k]; }
        float inv = 1.f / s;
        for (int k = 0; k < KC; ++k) wgt[t * KC + k] = e[k] * inv;
        if (FINAL) {
            float md = dist[0];
            for (int k = 1; k < KC; ++k) md = fminf(md, dist[k]);
            int ca = 0; float best = e[0] * inv;
            for (int k = 1; k < KC; ++k) {
                float wv = e[k] * inv;
                if (wv > best) { best = wv; ca = k; }
            }
            mind[t] = md;
            keys[t] = (float)ca * 1000.0f + (1.0f - best);
        }
    }
}

// ---- FUSED assign + update-pass1 (bit-exact weights; x parked in LDS) ----
__global__ __launch_bounds__(512) void asupd_k(const float* __restrict__ x,
                                               const float* __restrict__ cen0,
                                               int cbstride,
                                               float* __restrict__ part,
                                               float* __restrict__ denp) {
    int blk = blockIdx.x;        // b*SEGU + seg
    int b = blk >> 6, seg = blk & 63;
    constexpr int TSEG = N / SEGU;   // 16
    __shared__ float xs[TSEG][DM];   // 32 KB
    __shared__ float sw[TSEG][KC];
    int tid = threadIdx.x;
    int wv = tid >> 6, lane = tid & 63;
    int n0 = seg * TSEG;
    const float* cenb = cen0 + (size_t)b * cbstride;
#pragma unroll
    for (int half = 0; half < 2; ++half) {
        int tl = wv + half * 8;
        int t = (b << 10) + n0 + tl;
        const float4* xr = (const float4*)(x + (size_t)t * DM);
        float4 xv0 = xr[lane], xv1 = xr[lane + 64];
        ((float4*)&xs[tl][0])[lane] = xv0;
        ((float4*)&xs[tl][0])[lane + 64] = xv1;
        float d2[KC];
#pragma unroll
        for (int k = 0; k < KC; ++k) {
            const float4* cr = (const float4*)(cenb + k * DM);
            float4 c0 = cr[lane], c1 = cr[lane + 64];
            float dx = xv0.x - c0.x, dy = xv0.y - c0.y, dz = xv0.z - c0.z, dw = xv0.w - c0.w;
            float acc = dx * dx + dy * dy + dz * dz + dw * dw;
            dx = xv1.x - c1.x; dy = xv1.y - c1.y; dz = xv1.z - c1.z; dw = xv1.w - c1.w;
            acc += dx * dx + dy * dy + dz * dz + dw * dw;
            d2[k] = acc;
        }
#pragma unroll
        for (int k = 0; k < KC; ++k)
            for (int off = 32; off > 0; off >>= 1) d2[k] += __shfl_xor(d2[k], off);
        if (lane == 0) {
            float logit[KC], e[KC];
            float lm = -1e30f;
            for (int k = 0; k < KC; ++k) {
                float dist = sqrtf(d2[k] + 1e-12f);
                logit[k] = -dist / TEMP;
                lm = fmaxf(lm, logit[k]);
            }
            float s = 0.f;
            for (int k = 0; k < KC; ++k) { e[k] = expf(logit[k] - lm); s += e[k]; }
            float inv = 1.f / s;
            for (int k = 0; k < KC; ++k) sw[tl][k] = e[k] * inv;
        }
    }
    __syncthreads();
    int c = tid;
    float acc[KC] = {};
    for (int n = 0; n < TSEG; ++n) {
        float xv = xs[n][c];
#pragma unroll
        for (int k = 0; k < KC; ++k) acc[k] = fmaf(sw[n][k], xv, acc[k]);
    }
#pragma unroll
    for (int k = 0; k < KC; ++k)
        part[(((size_t)b * KC + k) * SEGU + seg) * DM + c] = acc[k];
    if (c < KC) {
        float dn = 0.f;
        for (int n = 0; n < TSEG; ++n) dn += sw[n][c];
        denp[((size_t)b * KC + c) * SEGU + seg] = dn;
    }
}

// ---- update: pass2 reduce ----
__global__ __launch_bounds__(512) void updr_k(const float* __restrict__ part,
                                              const float* __restrict__ denp,
                                              float* __restrict__ centers) {
    int bk = blockIdx.x;         // 0..B*KC-1
    int c = threadIdx.x;
    const float* pb = part + (size_t)bk * SEGU * DM + c;
    float acc = 0.f;
    for (int g = 0; g < SEGU; ++g) acc += pb[(size_t)g * DM];
    __shared__ float sden;
    if (c == 0) {
        float dn = 0.f;
        const float* db = denp + (size_t)bk * SEGU;
        for (int g = 0; g < SEGU; ++g) dn += db[g];
        sden = dn;
    }
    __syncthreads();
    centers[(size_t)bk * DM + c] = acc / (sden + 1e-8f);
}

// ---- merged sort (blocks 0..3) + importance (blocks 4..7) ----
__global__ __launch_bounds__(1024) void sortimp_k(const float* __restrict__ keys,
                                                  const float* __restrict__ mind,
                                                  int* __restrict__ ridx,
                                                  float* __restrict__ imp) {
    __shared__ unsigned long long a[1024];
    int tid = threadIdx.x;
    if (blockIdx.x < 4) {
        int b = blockIdx.x;
        unsigned int kb = __float_as_uint(keys[b * N + tid]);   // keys >= 0
        a[tid] = ((unsigned long long)kb << 32) | (unsigned int)tid;
        __syncthreads();
        for (int k = 2; k <= 1024; k <<= 1) {
            for (int j = k >> 1; j > 0; j >>= 1) {
                int ixj = tid ^ j;
                if (ixj > tid) {
                    unsigned long long x0 = a[tid], x1 = a[ixj];
                    bool up = ((tid & k) == 0);
                    bool sw = up ? (x0 > x1) : (x0 < x1);
                    if (sw) { a[tid] = x1; a[ixj] = x0; }
                }
                __syncthreads();
            }
        }
        ridx[b * N + tid] = (int)(a[tid] & 0xffffffffu);
    } else {
        int b = blockIdx.x - 4;
        float* red = (float*)a;
        float v = -mind[b * N + tid] / TEMP;
        red[tid] = v; __syncthreads();
        for (int s = 512; s > 0; s >>= 1) { if (tid < s) red[tid] = fmaxf(red[tid], red[tid + s]); __syncthreads(); }
        float m = red[0]; __syncthreads();
        float e = expf(v - m);
        red[tid] = e; __syncthreads();
        for (int s = 512; s > 0; s >>= 1) { if (tid < s) red[tid] += red[tid + s]; __syncthreads(); }
        imp[b * N + tid] = e / red[0];
    }
}

// ---- gather into combined 2-stream activation buffer + combined importance ----
__global__ __launch_bounds__(512) void gather_k(const float* __restrict__ x,
                                                const float* __restrict__ imp,
                                                const int* __restrict__ ridx,
                                                float* __restrict__ act0,
                                                float* __restrict__ impc) {
    int t = blockIdx.x;
    int b = t >> 10, j = t & (N - 1);
    int r = ridx[t];
    int c = threadIdx.x;
    float v = x[((size_t)(b << 10) + r) * DM + c];
    act0[(size_t)t * DM + c] = v;
    act0[((size_t)TT + (b << 10) + (N - 1 - j)) * DM + c] = v;
    if (c == 0) {
        float iv = imp[(b << 10) + r];
        impc[t] = iv;
        impc[TT + (b << 10) + (N - 1 - j)] = iv;
    }
}

// ---------------- merged weight prep ----------------
__device__ inline void tconv_body(const float* __restrict__ src, ushort* __restrict__ dst,
                                  int R, int C, int c0, int r0, float* tile /*32x33*/) {
    int tx = threadIdx.x & 31, ty = threadIdx.x >> 5;
#pragma unroll
    for (int j = 0; j < 4; ++j)
        tile[(ty + j * 8) * 33 + tx] = src[(size_t)(r0 + ty + j * 8) * C + c0 + tx];
    __syncthreads();
#pragma unroll
    for (int j = 0; j < 4; ++j)
        dst[(size_t)(c0 + ty + j * 8) * R + r0 + tx] = f2bf(tile[tx * 33 + ty + j * 8]);
}

__global__ __launch_bounds__(256) void prep_k(const float* __restrict__ in_w,
                                              const float* __restrict__ cm_w2,
                                              const float* __restrict__ out_w,
                                              const float* __restrict__ fusion_w,
                                              const float* __restrict__ xp_w,
                                              ushort* __restrict__ inwT, ushort* __restrict__ cmw2T,
                                              ushort* __restrict__ outwT, ushort* __restrict__ fusT,
                                              ushort* __restrict__ xpwT) {
    __shared__ float lds[256 * 33];
    int bx = blockIdx.x;
    if (bx < 4096) {                       // in_w: 4 layers x (64 x 16)
        int l = bx >> 10, i = bx & 1023;
        tconv_body(in_w + (size_t)l * DM * 2 * DI, inwT + (size_t)l * 2 * DI * DM,
                   DM, 2 * DI, (i & 63) * 32, (i >> 6) * 32, lds);
        return;
    }
    bx -= 4096;
    if (bx < 1024) {                       // cm_w2: 4 x (32 x 8)
        int l = bx >> 8, i = bx & 255;
        tconv_body(cm_w2 + (size_t)l * DI4 * DI, cmw2T + (size_t)l * DI * DI4,
                   DI4, DI, (i & 31) * 32, (i >> 5) * 32, lds);
        return;
    }
    bx -= 1024;
    if (bx < 2048) {                       // out_w: 4 x (16 x 32)
        int l = bx >> 9, i = bx & 511;
        tconv_body(out_w + (size_t)l * DI * DM, outwT + (size_t)l * DM * DI,
                   DI, DM, (i & 15) * 32, (i >> 4) * 32, lds);
        return;
    }
    bx -= 2048;
    if (bx < 512) {                        // fusion: 16 x 32
        tconv_body(fusion_w, fusT, 2 * DM, DM, (bx & 15) * 32, (bx >> 4) * 32, lds);
        return;
    }
    bx -= 512;
    {                                      // xp_w prep: 16 blocks
        int l = bx >> 2, chunk = bx & 3;
        int c0 = chunk * 256, tid = threadIdx.x;
        const float* src = xp_w + (size_t)l * DI * 33 + (size_t)c0 * 33;
        for (int i = tid; i < 256 * 33; i += 256) lds[i] = src[i];
        __syncthreads();
        ushort* dst = xpwT + (size_t)l * 128 * DI;
        for (int j = 0; j < 128; ++j) {
            ushort v = (j < 33) ? f2bf(lds[tid * 33 + j]) : (ushort)0;
            dst[(size_t)j * DI + c0 + tid] = v;
        }
    }
}

// ---------------- xssmP partials [4][TT2][128] -> xssmT [33][TT2] ----------------
__global__ __launch_bounds__(256) void tpose33_k(const float* __restrict__ xssmP,
                                                 float* __restrict__ xssmT) {
    int t0 = blockIdx.x * 64, tid = threadIdx.x;
    __shared__ float lds[64 * 129];
    const float* src = xssmP + (size_t)t0 * 128;
    const size_t PS = (size_t)TT2 * 128;
    for (int i = tid; i < 64 * 128; i += 256) {
        float v = src[i] + src[i + PS] + src[i + 2 * PS] + src[i + 3 * PS];
        lds[(i >> 7) * 129 + (i & 127)] = v;
    }
    __syncthreads();
    int tk = tid & 63, jq = tid >> 6;
    for (int j = jq; j < 33; j += 4)
        xssmT[(size_t)j * TT2 + t0 + tk] = lds[tk * 129 + j];
}

// ---------------- layernorm: wave-per-token over TT2, per-half layer params ----------------
__global__ __launch_bounds__(256) void ln_k(const float* __restrict__ xin,
                                            const float* __restrict__ ln_g,
                                            const float* __restrict__ ln_b,
                                            int lA, int lB,
                                            ushort* __restrict__ out) {
    int t = blockIdx.x * 4 + (threadIdx.x >> 6);
    int lane = threadIdx.x & 63;
    int l = (t < TT) ? lA : lB;
    const float* g = ln_g + (size_t)l * DM;
    const float* bt = ln_b + (size_t)l * DM;
    const float4* xr = (const float4*)(xin + (size_t)t * DM);
    float4 v0 = xr[lane * 2], v1 = xr[lane * 2 + 1];
    float s = ((v0.x + v0.y) + (v0.z + v0.w)) + ((v1.x + v1.y) + (v1.z + v1.w));
#pragma unroll
    for (int off = 32; off > 0; off >>= 1) s += __shfl_xor(s, off);
    float mu = s * (1.f / DM);
    float d0 = v0.x - mu, d1 = v0.y - mu, d2 = v0.z - mu, d3 = v0.w - mu;
    float d4 = v1.x - mu, d5 = v1.y - mu, d6 = v1.z - mu, d7 = v1.w - mu;
    float q = ((d0 * d0 + d1 * d1) + (d2 * d2 + d3 * d3)) + ((d4 * d4 + d5 * d5) + (d6 * d6 + d7 * d7));
#pragma unroll
    for (int off = 32; off > 0; off >>= 1) q += __shfl_xor(q, off);
    float rs = rsqrtf(q * (1.f / DM) + 1e-5f);
    const float4* gr = (const float4*)g;
    const float4* br = (const float4*)bt;
    float4 g0 = gr[lane * 2], g1 = gr[lane * 2 + 1];
    float4 b0 = br[lane * 2], b1 = br[lane * 2 + 1];
    uint4 pk;
    pk.x = (unsigned)f2bf(d0 * rs * g0.x + b0.x) | ((unsigned)f2bf(d1 * rs * g0.y + b0.y) << 16);
    pk.y = (unsigned)f2bf(d2 * rs * g0.z + b0.z) | ((unsigned)f2bf(d3 * rs * g0.w + b0.w) << 16);
    pk.z = (unsigned)f2bf(d4 * rs * g1.x + b1.x) | ((unsigned)f2bf(d5 * rs * g1.y + b1.y) << 16);
    pk.w = (unsigned)f2bf(d6 * rs * g1.z + b1.z) | ((unsigned)f2bf(d7 * rs * g1.w + b1.w) << 16);
    *(uint4*)(out + (size_t)t * DM + lane * 8) = pk;
}

// ---------------- MFMA bf16 GEMM, dbuf gld16; per-row-half B/bias; split-K via gridDim.z ----------------
template <bool BF16OUT>
__global__ __launch_bounds__(256) void mgemm_k(const ushort* __restrict__ A, int lda,
                                               const ushort* __restrict__ BtA,
                                               const ushort* __restrict__ BtB, int ldb,
                                               const float* __restrict__ biasA,
                                               const float* __restrict__ biasB,
                                               const float* __restrict__ add, int ldadd,
                                               void* __restrict__ Cout, int ldc, int Kdim,
                                               size_t czs) {
    __shared__ short8v As[2][128 * 4];
    __shared__ short8v Bs[2][128 * 4];
    int tid = threadIdx.x;
    int lane = tid & 63, wid = tid >> 6;
    int row0 = blockIdx.y * 128, col0 = blockIdx.x * 128;
    const ushort* Bt = (row0 < TT || !BtB) ? BtA : BtB;
    const float* bias = (row0 < TT || !BtB) ? biasA : biasB;
    int wr = (wid >> 1) * 64, wc = (wid & 1) * 64;
    float4v acc[4][4];
#pragma unroll
    for (int i = 0; i < 4; ++i)
#pragma unroll
        for (int j = 0; j < 4; ++j)
#pragma unroll
            for (int r = 0; r < 4; ++r) acc[i][j][r] = 0.f;

    int rq0 = wid * 32 + (lane >> 2);
    int rq1 = rq0 + 16;
    int clds = lane & 3;
    int cs0 = clds ^ ((rq0 >> 1) & 3);
    int cs1 = clds ^ ((rq1 >> 1) & 3);
    const ushort* aSrc0 = A + (size_t)(row0 + rq0) * lda + cs0 * 8;
    const ushort* aSrc1 = A + (size_t)(row0 + rq1) * lda + cs1 * 8;
    const ushort* bSrc0 = Bt + (size_t)(col0 + rq0) * ldb + cs0 * 8;
    const ushort* bSrc1 = Bt + (size_t)(col0 + rq1) * ldb + cs1 * 8;

    int fr = lane & 15, kg = lane >> 4;
    int sf = kg ^ ((fr >> 1) & 3);

    int kslice = Kdim / (int)gridDim.z;
    int kbeg = (int)blockIdx.z * kslice;
    int T = kslice / 32;

    gld16(aSrc0 + kbeg, &As[0][wid * 128]);
    gld16(aSrc1 + kbeg, &As[0][wid * 128 + 64]);
    gld16(bSrc0 + kbeg, &Bs[0][wid * 128]);
    gld16(bSrc1 + kbeg, &Bs[0][wid * 128 + 64]);
    __syncthreads();
    int cur = 0;
    for (int i = 0; i < T; ++i) {
        if (i + 1 < T) {
            int kn = kbeg + (i + 1) * 32;
            gld16(aSrc0 + kn, &As[cur ^ 1][wid * 128]);
            gld16(aSrc1 + kn, &As[cur ^ 1][wid * 128 + 64]);
            gld16(bSrc0 + kn, &Bs[cur ^ 1][wid * 128]);
            gld16(bSrc1 + kn, &Bs[cur ^ 1][wid * 128 + 64]);
        }
        short8v af[4], bf[4];
#pragma unroll
        for (int mb = 0; mb < 4; ++mb) af[mb] = As[cur][(wr + mb * 16 + fr) * 4 + sf];
#pragma unroll
        for (int nb = 0; nb < 4; ++nb) bf[nb] = Bs[cur][(wc + nb * 16 + fr) * 4 + sf];
#pragma unroll
        for (int mb = 0; mb < 4; ++mb)
#pragma unroll
            for (int nb = 0; nb < 4; ++nb)
                acc[mb][nb] = __builtin_amdgcn_mfma_f32_16x16x32_bf16(af[mb], bf[nb], acc[mb][nb], 0, 0, 0);
        __syncthreads();
        cur ^= 1;
    }
    ushort* cu = (ushort*)Cout + (size_t)blockIdx.z * czs;
    float* cf = (float*)Cout + (size_t)blockIdx.z * czs;
#pragma unroll
    for (int mb = 0; mb < 4; ++mb) {
        int r_ = row0 + wr + mb * 16 + kg * 4;
#pragma unroll
        for (int nb = 0; nb < 4; ++nb) {
            int c_ = col0 + wc + nb * 16 + fr;
            float bz = bias ? bias[c_] : 0.f;
#pragma unroll
            for (int r = 0; r < 4; ++r) {
                float o = acc[mb][nb][r] + bz;
                if (add) o += add[(size_t)(r_ + r) * ldadd + c_];
                if (BF16OUT) cu[(size_t)(r_ + r) * ldc + c_] = f2bf(o);
                else         cf[(size_t)(r_ + r) * ldc + c_] = o;
            }
        }
    }
}

// ---------------- h1-fused cm_w2 GEMM, dbuf, per-row-half layer (bf16 modl out) ----------------
__global__ __launch_bounds__(256) void mgemmH_k(const float* __restrict__ impc,
                                                const float* __restrict__ cm_w1,
                                                const float* __restrict__ cm_b1,
                                                const ushort* __restrict__ cmw2T,
                                                const float* __restrict__ cm_b2,
                                                int lA, int lB,
                                                ushort* __restrict__ Cout, int ldc) {
    __shared__ short8v As[2][128 * 4];
    __shared__ short8v Bs[2][128 * 4];
    int tid = threadIdx.x;
    int lane = tid & 63, wid = tid >> 6;
    int row0 = blockIdx.y * 128, col0 = blockIdx.x * 128;
    int l = (row0 < TT) ? lA : lB;
    const float* w1 = cm_w1 + (size_t)l * DI4;
    const float* b1 = cm_b1 + (size_t)l * DI4;
    const ushort* Bt = cmw2T + (size_t)l * DI * DI4;
    const float* bias = cm_b2 + (size_t)l * DI;
    int wr = (wid >> 1) * 64, wc = (wid & 1) * 64;
    float4v acc[4][4];
#pragma unroll
    for (int i = 0; i < 4; ++i)
#pragma unroll
        for (int j = 0; j < 4; ++j)
#pragma unroll
            for (int r = 0; r < 4; ++r) acc[i][j][r] = 0.f;

    int rq0 = wid * 32 + (lane >> 2);
    int rq1 = rq0 + 16;
    int clds = lane & 3;
    int cs0 = clds ^ ((rq0 >> 1) & 3);
    int cs1 = clds ^ ((rq1 >> 1) & 3);
    float imp0 = impc[row0 + rq0];
    float imp1 = impc[row0 + rq1];
    const ushort* bSrc0 = Bt + (size_t)(col0 + rq0) * DI4 + cs0 * 8;
    const ushort* bSrc1 = Bt + (size_t)(col0 + rq1) * DI4 + cs1 * 8;

    int fr = lane & 15, kg = lane >> 4;
    int sf = kg ^ ((fr >> 1) & 3);

    auto mkA = [&](int k0, float impv, int cs, short8v* dst) {
        float4 w0 = *(const float4*)(w1 + k0 + cs * 8);
        float4 w4 = *(const float4*)(w1 + k0 + cs * 8 + 4);
        float4 bq0 = *(const float4*)(b1 + k0 + cs * 8);
        float4 bq4 = *(const float4*)(b1 + k0 + cs * 8 + 4);
        short8v p;
        p[0] = (short)f2bf(fmaxf(fmaf(impv, w0.x, bq0.x), 0.f));
        p[1] = (short)f2bf(fmaxf(fmaf(impv, w0.y, bq0.y), 0.f));
        p[2] = (short)f2bf(fmaxf(fmaf(impv, w0.z, bq0.z), 0.f));
        p[3] = (short)f2bf(fmaxf(fmaf(impv, w0.w, bq0.w), 0.f));
        p[4] = (short)f2bf(fmaxf(fmaf(impv, w4.x, bq4.x), 0.f));
        p[5] = (short)f2bf(fmaxf(fmaf(impv, w4.y, bq4.y), 0.f));
        p[6] = (short)f2bf(fmaxf(fmaf(impv, w4.z, bq4.z), 0.f));
        p[7] = (short)f2bf(fmaxf(fmaf(impv, w4.w, bq4.w), 0.f));
        *dst = p;
    };

    mkA(0, imp0, cs0, &As[0][rq0 * 4 + clds]);
    mkA(0, imp1, cs1, &As[0][rq1 * 4 + clds]);
    gld16(bSrc0, &Bs[0][wid * 128]);
    gld16(bSrc1, &Bs[0][wid * 128 + 64]);
    __syncthreads();
    int cur = 0;
    constexpr int T = DI4 / 32;   // 8
    for (int i = 0; i < T; ++i) {
        if (i + 1 < T) {
            int kn = (i + 1) * 32;
            mkA(kn, imp0, cs0, &As[cur ^ 1][rq0 * 4 + clds]);
            mkA(kn, imp1, cs1, &As[cur ^ 1][rq1 * 4 + clds]);
            gld16(bSrc0 + kn, &Bs[cur ^ 1][wid * 128]);
            gld16(bSrc1 + kn, &Bs[cur ^ 1][wid * 128 + 64]);
        }
        short8v af[4], bf[4];
#pragma unroll
        for (int mb = 0; mb < 4; ++mb) af[mb] = As[cur][(wr + mb * 16 + fr) * 4 + sf];
#pragma unroll
        for (int nb = 0; nb < 4; ++nb) bf[nb] = Bs[cur][(wc + nb * 16 + fr) * 4 + sf];
#pragma unroll
        for (int mb = 0; mb < 4; ++mb)
#pragma unroll
            for (int nb = 0; nb < 4; ++nb)
                acc[mb][nb] = __builtin_amdgcn_mfma_f32_16x16x32_bf16(af[mb], bf[nb], acc[mb][nb], 0, 0, 0);
        __syncthreads();
        cur ^= 1;
    }
#pragma unroll
    for (int mb = 0; mb < 4; ++mb) {
        int r_ = row0 + wr + mb * 16 + kg * 4;
#pragma unroll
        for (int nb = 0; nb < 4; ++nb) {
            int c_ = col0 + wc + nb * 16 + fr;
            float bz = bias[c_];
#pragma unroll
            for (int r = 0; r < 4; ++r)
                Cout[(size_t)(r_ + r) * ldc + c_] = f2bf(acc[mb][nb][r] + bz);
        }
    }
}

// ---------------- depthwise causal conv + silu (ushort2), per-half layer ----------------
__global__ __launch_bounds__(256) void conv_k(const ushort* __restrict__ xz,
                                              const float* __restrict__ conv_w,
                                              const float* __restrict__ conv_b,
                                              int lA, int lB,
                                              ushort* __restrict__ xcb) {
    int gid = blockIdx.x * 256 + threadIdx.x;   // pair index over TT2*DI/2
    int p = gid & (DI / 2 - 1);
    int d = p * 2;
    int t = gid >> 9;
    int n = t & (N - 1);
    int l = (t < TT) ? lA : lB;
    const float* cw = conv_w + (size_t)l * DI * DC;
    const float* cb = conv_b + (size_t)l * DI;
    float acc0 = cb[d], acc1 = cb[d + 1];
    const ushort* base = xz + (size_t)t * (2 * DI) + d;
    float4 w0 = *(const float4*)(cw + d * DC);
    float4 w1 = *(const float4*)(cw + (d + 1) * DC);
    float wk0[4] = {w0.x, w0.y, w0.z, w0.w};
    float wk1[4] = {w1.x, w1.y, w1.z, w1.w};
#pragma unroll
    for (int k = 0; k < DC; ++k) {
        int nn = n - (DC - 1) + k;
        if (nn >= 0) {
            unsigned u = *(const unsigned*)(base + (long)(nn - n) * (2 * DI));
            acc0 = fmaf(bf2f((ushort)(u & 0xffff)), wk0[k], acc0);
            acc1 = fmaf(bf2f((ushort)(u >> 16)), wk1[k], acc1);
        }
    }
    float s0 = acc0 * sigm(acc0);
    float s1 = acc1 * sigm(acc1);
    unsigned o = (unsigned)f2bf(s0) | ((unsigned)f2bf(s1) << 16);
    *(unsigned*)(xcb + (size_t)t * DI + d) = o;
}

// ================= segmented scan (batched: b 0..7, per-half layer) =================
// Phase A: computes delta from modl; local scan + transfer product; writes delf.
__global__ __launch_bounds__(256) void scanA_k(const ushort* __restrict__ modl,
                                               const ushort* __restrict__ xcb,
                                               const float* __restrict__ xssmT,
                                               const float* __restrict__ Alog0,
                                               const float* __restrict__ dtw0,
                                               const float* __restrict__ dtb0,
                                               int lA, int lB,
                                               float* __restrict__ delf,
                                               float* __restrict__ hloc,
                                               float* __restrict__ Pp) {
    int blk = blockIdx.x;
    int seg = blk & 15;
    int dblk = (blk >> 4) & 63;
    int b = blk >> 10;                 // 0..7
    int l = (b < 4) ? lA : lB;
    const float* Alog = Alog0 + (size_t)l * DI * DS;
    const float* dtw = dtw0 + (size_t)l * DI;
    const float* dtb = dtb0 + (size_t)l * DI;
    int d0 = dblk * 16;
    int tid = threadIdx.x;
    int lane = tid & 63, wave = tid >> 6;
    int s = lane & 15, dd = lane >> 4;
    int dl = wave * 4 + dd, d = d0 + dl;
    float A2 = -__expf(Alog[d * DS + s]) * LOG2E;
    size_t tokbase = (size_t)b * N + (size_t)seg * SLEN;

    __shared__ float sdl[16][68];
    __shared__ float sxc[16][68];
    __shared__ float sBv[16][68];

    int lc = tid & 15, lr = tid >> 4;
    float dtwv = dtw[d0 + lc], dtbv = dtb[d0 + lc];
    const ushort* mbase = modl + tokbase * DI + d0 + lc;
    const ushort* xbase = xcb + tokbase * DI + d0 + lc;
    const float* drow = xssmT + tokbase;
    const float* Brow = xssmT + (size_t)(1 + lc) * TT2 + tokbase;
#pragma unroll
    for (int q = 0; q < 4; ++q) {
        int tok = q * 16 + lr;
        float mo   = bf2f(mbase[(size_t)tok * DI]);
        float draw = drow[tok];
        float xcv  = bf2f(xbase[(size_t)tok * DI]);
        float Bv   = Brow[tok];
        float a = draw * dtwv + dtbv;
        float sp = softp(a);
        float mod = sigm(mo);
        float dlv = sp * (1.f + mod);
        sdl[lc][tok] = dlv;
        delf[(tokbase + tok) * DI + d0 + lc] = dlv;
        sxc[lc][tok] = xcv;
        sBv[lc][tok] = Bv;
    }
    __syncthreads();
    float h = 0.f, P = 1.f;
#pragma unroll
    for (int g = 0; g < 8; ++g) {
        float4 dl4a = *(const float4*)&sdl[dl][g * 8];
        float4 dl4b = *(const float4*)&sdl[dl][g * 8 + 4];
        float4 xc4a = *(const float4*)&sxc[dl][g * 8];
        float4 xc4b = *(const float4*)&sxc[dl][g * 8 + 4];
        float4 B4a  = *(const float4*)&sBv[s][g * 8];
        float4 B4b  = *(const float4*)&sBv[s][g * 8 + 4];
        float dlt[8] = {dl4a.x, dl4a.y, dl4a.z, dl4a.w, dl4b.x, dl4b.y, dl4b.z, dl4b.w};
        float xcv[8] = {xc4a.x, xc4a.y, xc4a.z, xc4a.w, xc4b.x, xc4b.y, xc4b.z, xc4b.w};
        float Bv8[8] = {B4a.x, B4a.y, B4a.z, B4a.w, B4b.x, B4b.y, B4b.z, B4b.w};
        float a8[8], b8[8];
#pragma unroll
        for (int j = 0; j < 8; ++j) {
            a8[j] = hexp2(dlt[j] * A2);
            b8[j] = (dlt[j] * Bv8[j]) * xcv[j];
        }
#pragma unroll
        for (int j = 0; j < 8; ++j) { h = fmaf(a8[j], h, b8[j]); P *= a8[j]; }
    }
    size_t idx = (size_t)blk * 256 + tid;
    hloc[idx] = h;
    Pp[idx] = P;
}

__global__ __launch_bounds__(256) void scanB_k(const float* __restrict__ hloc,
                                               const float* __restrict__ Pp,
                                               float* __restrict__ h0g) {
    int blk = blockIdx.x;     // 0..511 (8*64)
    int tid = threadIdx.x;
    size_t base = (size_t)blk * SEG * 256 + tid;
    float h = 0.f;
    for (int g = 0; g < SEG; ++g) {
        size_t i = base + (size_t)g * 256;
        h0g[i] = h;
        h = fmaf(Pp[i], h, hloc[i]);
    }
}

// Phase C: re-run segment from true h0. State-reduce over s done IN-REGISTER via
// shfl_xor butterfly within each 16-lane group (lane = dd*16 + s) — removes the
// sP LDS buffer (17.4 KB) and all main-loop barriers; lane s==0 writes y.
__global__ __launch_bounds__(256) void scanC_k(const float* __restrict__ delf,
                                               const ushort* __restrict__ xcb,
                                               const float* __restrict__ xssmT,
                                               const float* __restrict__ Alog0,
                                               const float* __restrict__ Dp0,
                                               const ushort* __restrict__ xz,
                                               int lA, int lB,
                                               const float* __restrict__ h0g,
                                               ushort* __restrict__ y) {
    int blk = blockIdx.x;
    int seg = blk & 15;
    int dblk = (blk >> 4) & 63;
    int b = blk >> 10;                 // 0..7
    int l = (b < 4) ? lA : lB;
    const float* Alog = Alog0 + (size_t)l * DI * DS;
    const float* Dp = Dp0 + (size_t)l * DI;
    int d0 = dblk * 16;
    int tid = threadIdx.x;
    int lane = tid & 63, wave = tid >> 6;
    int s = lane & 15, dd = lane >> 4;
    int dl = wave * 4 + dd, d = d0 + dl;
    float A2 = -__expf(Alog[d * DS + s]) * LOG2E;
    float dpv = Dp[d];
    size_t tokbase = (size_t)b * N + (size_t)seg * SLEN;

    __shared__ float sdl[16][68];
    __shared__ float sxc[16][68];
    __shared__ float sBv[16][68];
    __shared__ float sCv[16][68];
    __shared__ float szv[16][68];

    int lc = tid & 15, lr = tid >> 4;
    const float* dbase = delf + tokbase * DI + d0 + lc;
    const ushort* xbase = xcb + tokbase * DI + d0 + lc;
    const ushort* zbase = xz + tokbase * (2 * DI) + DI + d0 + lc;
    const float* Brow = xssmT + (size_t)(1 + lc) * TT2 + tokbase;
    const float* Crow = xssmT + (size_t)(1 + DS + lc) * TT2 + tokbase;
#pragma unroll
    for (int q = 0; q < 4; ++q) {
        int tok = q * 16 + lr;
        sdl[lc][tok] = dbase[(size_t)tok * DI];
        sxc[lc][tok] = bf2f(xbase[(size_t)tok * DI]);
        sBv[lc][tok] = Brow[tok];
        sCv[lc][tok] = Crow[tok];
        szv[lc][tok] = bf2f(zbase[(size_t)tok * (2 * DI)]);
    }
    __syncthreads();
    float h = h0g[(size_t)blk * 256 + tid];
    for (int g = 0; g < 8; ++g) {              // 8-token groups, barrier-free
        float4 dl4a = *(const float4*)&sdl[dl][g * 8];
        float4 dl4b = *(const float4*)&sdl[dl][g * 8 + 4];
        float4 xc4a = *(const float4*)&sxc[dl][g * 8];
        float4 xc4b = *(const float4*)&sxc[dl][g * 8 + 4];
        float4 B4a  = *(const float4*)&sBv[s][g * 8];
        float4 B4b  = *(const float4*)&sBv[s][g * 8 + 4];
        float4 C4a  = *(const float4*)&sCv[s][g * 8];
        float4 C4b  = *(const float4*)&sCv[s][g * 8 + 4];
        float4 z4a  = *(const float4*)&szv[dl][g * 8];
        float4 z4b  = *(const float4*)&szv[dl][g * 8 + 4];
        float dlt[8] = {dl4a.x, dl4a.y, dl4a.z, dl4a.w, dl4b.x, dl4b.y, dl4b.z, dl4b.w};
        float xcv[8] = {xc4a.x, xc4a.y, xc4a.z, xc4a.w, xc4b.x, xc4b.y, xc4b.z, xc4b.w};
        float Bv8[8] = {B4a.x, B4a.y, B4a.z, B4a.w, B4b.x, B4b.y, B4b.z, B4b.w};
        float Cv8[8] = {C4a.x, C4a.y, C4a.z, C4a.w, C4b.x, C4b.y, C4b.z, C4b.w};
        float zv8[8] = {z4a.x, z4a.y, z4a.z, z4a.w, z4b.x, z4b.y, z4b.z, z4b.w};
        float a8[8], b8[8];
#pragma unroll
        for (int j = 0; j < 8; ++j) {
            a8[j] = hexp2(dlt[j] * A2);
            b8[j] = (dlt[j] * Bv8[j]) * xcv[j];
        }
#pragma unroll
        for (int j = 0; j < 8; ++j) {
            h = fmaf(a8[j], h, b8[j]);
            float p = h * Cv8[j];
            p += __shfl_xor(p, 1);
            p += __shfl_xor(p, 2);
            p += __shfl_xor(p, 4);
            p += __shfl_xor(p, 8);
            if (s == 0) {
                int tok = g * 8 + j;
                float zv = zv8[j];
                float sg = sigm(zv);
                y[(tokbase + tok) * DI + d] = f2bf((p + xcv[j] * dpv) * (zv * sg));
            }
        }
    }
}

// ---------------- concat [xf | flip(xb)] from combined act0 -> bf16 ----------------
__global__ __launch_bounds__(256) void concat_k(const float* __restrict__ act0,
                                                ushort* __restrict__ cat) {
    int gid = blockIdx.x * 256 + threadIdx.x;   // TT*DM
    int t = gid >> 9;
    int c = gid & (DM - 1);
    int b = t >> 10, j = t & (N - 1);
    cat[(size_t)t * (2 * DM) + c] = f2bf(act0[(size_t)t * DM + c]);
    cat[(size_t)t * (2 * DM) + DM + c] =
        f2bf(act0[((size_t)TT + (b << 10) + (N - 1 - j)) * DM + c]);
}

// ---------------- final: scatter by ridx + layernorm ----------------
__global__ __launch_bounds__(256) void final_k(const float* __restrict__ fus,
                                               const int* __restrict__ ridx,
                                               const float* __restrict__ g,
                                               const float* __restrict__ bt,
                                               float* __restrict__ out) {
    int t = blockIdx.x, tid = threadIdx.x;
    int b = t >> 10;
    int r = ridx[t];
    const float* xr = fus + (size_t)t * DM;
    __shared__ float red[256];
    float v0 = xr[tid], v1 = xr[tid + 256];
    red[tid] = v0 + v1; __syncthreads();
    for (int st = 128; st > 0; st >>= 1) { if (tid < st) red[tid] += red[tid + st]; __syncthreads(); }
    float mu = red[0] * (1.f / DM); __syncthreads();
    float d0 = v0 - mu, d1 = v1 - mu;
    red[tid] = d0 * d0 + d1 * d1; __syncthreads();
    for (int st = 128; st > 0; st >>= 1) { if (tid < st) red[tid] += red[tid + st]; __syncthreads(); }
    float rs = rsqrtf(red[0] * (1.f / DM) + 1e-5f);
    float* orow = out + ((size_t)(b << 10) + r) * DM;
    orow[tid] = d0 * rs * g[tid] + bt[tid];
    orow[tid + 256] = d1 * rs * g[tid + 256] + bt[tid + 256];
}

// ---------------- host ----------------
extern "C" void kernel_launch(void* const* d_in, const int* in_sizes, int n_in,
                              void* d_out, int out_size, void* d_ws, size_t ws_size,
                              hipStream_t stream) {
    const float* x            = (const float*)d_in[0];
    const float* centers_init = (const float*)d_in[1];
    const float* in_w         = (const float*)d_in[2];
    const float* conv_w       = (const float*)d_in[3];
    const float* conv_b       = (const float*)d_in[4];
    const float* xp_w         = (const float*)d_in[5];
    const float* dt_w         = (const float*)d_in[6];
    const float* dt_b         = (const float*)d_in[7];
    const float* cm_w1        = (const float*)d_in[8];
    const float* cm_b1        = (const float*)d_in[9];
    const float* cm_w2        = (const float*)d_in[10];
    const float* cm_b2        = (const float*)d_in[11];
    const float* A_log        = (const float*)d_in[12];
    const float* D_p          = (const float*)d_in[13];
    const float* out_w        = (const float*)d_in[14];
    const float* ln_g         = (const float*)d_in[15];
    const float* ln_b         = (const float*)d_in[16];
    const float* fusion_w     = (const float*)d_in[17];
    const float* fusion_b     = (const float*)d_in[18];
    const float* fn_g         = (const float*)d_in[19];
    const float* fn_b         = (const float*)d_in[20];

    float* W = (float*)d_ws;
    size_t off = 0;
    auto alloc = [&](size_t n) { float* p = W + off; off += (n + 15) & ~(size_t)15; return p; };
    auto allocU = [&](size_t n) { ushort* p = (ushort*)(W + off); off += ((n + 1) / 2 + 15) & ~(size_t)15; return p; };
    float* centers = alloc((size_t)Bb * KC * DM);
    float* wgt     = alloc((size_t)TT * KC);
    float* mind    = alloc(TT);
    float* keys    = alloc(TT);
    float* imp     = alloc(TT);
    float* impc    = alloc(TT2);
    float* denp    = alloc((size_t)Bb * KC * SEGU);
    float* act0    = alloc((size_t)TT2 * DM);      // combined fwd|bwd activations
    float* act1    = alloc((size_t)TT2 * DM);      // pair intermediate; aliased as fus
    float* xssmT   = alloc((size_t)TT2 * 33);
    float* delf    = alloc((size_t)TT2 * DI);      // f32 delta (scanA -> scanC); aliases kmeans part
    float* hloc    = alloc((size_t)8 * 64 * SEG * 256);   // hloc+Pp aliased by xssmP (16MB)
    float* Pp      = alloc((size_t)8 * 64 * SEG * 256);
    float* h0g     = alloc((size_t)8 * 64 * SEG * 256);
    ushort* xz     = allocU((size_t)TT2 * 2 * DI); // bf16 xz; reused as bf16 cat
    ushort* modl   = allocU((size_t)TT2 * DI);
    ushort* yb     = allocU((size_t)TT2 * DI);     // scanC out; aliased as xnb (disjoint)
    ushort* xcb    = allocU((size_t)TT2 * DI);
    ushort* inwT   = allocU((size_t)L4 * 2 * DI * DM);
    ushort* cmw2T  = allocU((size_t)L4 * DI * DI4);
    ushort* outwT  = allocU((size_t)L4 * DM * DI);
    ushort* fusT   = allocU((size_t)DM * 2 * DM);
    ushort* xpwT   = allocU((size_t)L4 * 128 * DI);
    int* ridx = (int*)(W + off); off += TT;
    float* part = delf;           // kmeans partials alias delf (disjoint in time)
    float* xssmP = hloc;          // 4 split-K partials (16MB) alias hloc+Pp, disjoint in time
    ushort* xnb = yb;             // ln out aliases yb (live ranges disjoint within a pair)
    float* fus = act1;            // fusion out aliases act1 (dead after pair 1)

    // ---- merged weight prep ----
    prep_k<<<7696, 256, 0, stream>>>(in_w, cm_w2, out_w, fusion_w, xp_w,
                                     inwT, cmw2T, outwT, fusT, xpwT);

    // ---- k-means (fused assign+updp per iteration) ----
    for (int it = 0; it < 3; ++it) {
        if (it == 0) asupd_k<<<Bb * SEGU, 512, 0, stream>>>(x, centers_init, 0, part, denp);
        else         asupd_k<<<Bb * SEGU, 512, 0, stream>>>(x, centers, KC * DM, part, denp);
        updr_k<<<Bb * KC, 512, 0, stream>>>(part, denp, centers);
    }
    assign_k<true><<<TT / 4, 256, 0, stream>>>(x, centers, KC * DM, wgt, mind, keys);
    sortimp_k<<<8, 1024, 0, stream>>>(keys, mind, ridx, imp);
    gather_k<<<TT, 512, 0, stream>>>(x, imp, ridx, act0, impc);

    // ---- 2 layer-pairs, each batching fwd (rows 0..TT) and bwd (rows TT..TT2) ----
    float* pin[2]  = {act0, act1};
    float* pout[2] = {act1, act0};
    for (int pr = 0; pr < 2; ++pr) {
        int lA = pr, lB = pr + 2;
        float* actin = pin[pr];
        float* actout = pout[pr];
        ln_k<<<TT2 / 4, 256, 0, stream>>>(actin, ln_g, ln_b, lA, lB, xnb);
        {   // in_w GEMM: M=TT2, N=2048, K=512, bf16 out
            dim3 g(2 * DI / 128, TT2 / 128, 1);
            mgemm_k<true><<<g, 256, 0, stream>>>(xnb, DM,
                inwT + (size_t)lA * 2 * DI * DM, inwT + (size_t)lB * 2 * DI * DM, DM,
                nullptr, nullptr, nullptr, 0, xz, 2 * DI, DM, 0);
        }
        conv_k<<<(TT2 * DI / 2) / 256, 256, 0, stream>>>(xz, conv_w, conv_b, lA, lB, xcb);
        {   // xssm GEMM: split-K=4
            dim3 g(1, TT2 / 128, 4);
            mgemm_k<false><<<g, 256, 0, stream>>>(xcb, DI,
                xpwT + (size_t)lA * 128 * DI, xpwT + (size_t)lB * 128 * DI, DI,
                nullptr, nullptr, nullptr, 0, xssmP, 128, DI, (size_t)TT2 * 128);
        }
        tpose33_k<<<TT2 / 64, 256, 0, stream>>>(xssmP, xssmT);
        mgemmH_k<<<dim3(DI / 128, TT2 / 128), 256, 0, stream>>>(impc, cm_w1, cm_b1, cmw2T, cm_b2,
                                                                lA, lB, modl, DI);
        scanA_k<<<8 * 64 * SEG, 256, 0, stream>>>(modl, xcb, xssmT, A_log, dt_w, dt_b,
                                                  lA, lB, delf, hloc, Pp);
        scanB_k<<<8 * 64, 256, 0, stream>>>(hloc, Pp, h0g);
        scanC_k<<<8 * 64 * SEG, 256, 0, stream>>>(delf, xcb, xssmT, A_log, D_p, xz,
                                                  lA, lB, h0g, yb);
        {   // out_w GEMM: M=TT2, N=512, K=1024, +residual
            dim3 g(DM / 128, TT2 / 128, 1);
            mgemm_k<false><<<g, 256, 0, stream>>>(yb, DI,
                outwT + (size_t)lA * DM * DI, outwT + (size_t)lB * DM * DI, DI,
                nullptr, nullptr, actin, DM, actout, DM, DI, 0);
        }
    }

    // ---- fusion + restore + final LN ----
    ushort* catb = xz;
    concat_k<<<(TT * DM) / 256, 256, 0, stream>>>(act0, catb);
    {
        dim3 g(DM / 128, TT / 128, 1);
        mgemm_k<false><<<g, 256, 0, stream>>>(catb, 2 * DM, fusT, nullptr, 2 * DM,
                                              fusion_b, nullptr, nullptr, 0, fus, DM, 2 * DM, 0);
    }
    final_k<<<TT, 256, 0, stream>>>(fus, ridx, fn_g, fn_b, (float*)d_out);
}

// Round 23
// 567.047 us; speedup vs baseline: 1.2334x; 1.2334x over previous
//
#include <hip/hip_runtime.h>
#include <math.h>

// ---------------- constants ----------------
constexpr int DM = 512, DS = 16, DC = 4, DI = 1024, DI4 = 256, KC = 5;
constexpr int Bb = 4, N = 1024, L4 = 4, TT = Bb * N, TT2 = 2 * TT;
constexpr float TEMP = 0.5f;
constexpr int SEG = 16;          // scan segments per sequence (R20: 32 regressed; 16 optimal)
constexpr int SLEN = N / SEG;    // 64 tokens per segment
constexpr int SEGU = 64;         // kmeans-update segments
constexpr float LOG2E = 1.44269504f;

typedef __attribute__((ext_vector_type(8))) short short8v;
typedef __attribute__((ext_vector_type(4))) float float4v;

__device__ inline ushort f2bf(float f) {
    union { float f; unsigned u; } v; v.f = f;
    unsigned r = v.u + 0x7FFFu + ((v.u >> 16) & 1u);
    return (ushort)(r >> 16);
}
__device__ inline float bf2f(ushort u) {
    union { unsigned u; float f; } v; v.u = ((unsigned)u) << 16;
    return v.f;
}
__device__ inline void gld16(const void* g, void* lds) {
    __builtin_amdgcn_global_load_lds(
        (const __attribute__((address_space(1))) unsigned int*)g,
        (__attribute__((address_space(3))) unsigned int*)lds, 16, 0, 0);
}
// hardware exp2 (single v_exp_f32)
__device__ inline float hexp2(float x) { return __builtin_amdgcn_exp2f(x); }
// fast sigmoid: v_rcp_f32 approx (rel err ~1e-5, << bf16 rounding)
__device__ inline float sigm(float x) {
    return __builtin_amdgcn_rcpf(1.f + __expf(-x));
}
// fast softplus: hw log/exp (log1p precision loss only where delta is negligibly small)
__device__ inline float softp(float a) {
    return (a > 20.f) ? a : __logf(1.f + __expf(a));
}

// ---------------- k-means assign (wave-per-token, float4) ----------------
template <bool FINAL>
__global__ __launch_bounds__(256) void assign_k(const float* __restrict__ x,
                                                const float* __restrict__ cen0,
                                                int cbstride,
                                                float* __restrict__ wgt,
                                                float* __restrict__ mind,
                                                float* __restrict__ keys) {
    int t = blockIdx.x * 4 + (threadIdx.x >> 6);   // token
    int b = t >> 10;
    int lane = threadIdx.x & 63;
    const float4* xr = (const float4*)(x + (size_t)t * DM);
    float4 xv0 = xr[lane], xv1 = xr[lane + 64];
    const float* cenb = cen0 + (size_t)b * cbstride;
    float d2[KC];
#pragma unroll
    for (int k = 0; k < KC; ++k) {
        const float4* cr = (const float4*)(cenb + k * DM);
        float4 c0 = cr[lane], c1 = cr[lane + 64];
        float dx = xv0.x - c0.x, dy = xv0.y - c0.y, dz = xv0.z - c0.z, dw = xv0.w - c0.w;
        float acc = dx * dx + dy * dy + dz * dz + dw * dw;
        dx = xv1.x - c1.x; dy = xv1.y - c1.y; dz = xv1.z - c1.z; dw = xv1.w - c1.w;
        acc += dx * dx + dy * dy + dz * dz + dw * dw;
        d2[k] = acc;
    }
#pragma unroll
    for (int k = 0; k < KC; ++k)
        for (int off = 32; off > 0; off >>= 1) d2[k] += __shfl_xor(d2[k], off);
    if (lane == 0) {
        float dist[KC], logit[KC], e[KC];
        float lm = -1e30f;
        for (int k = 0; k < KC; ++k) {
            dist[k] = sqrtf(d2[k] + 1e-12f);
            logit[k] = -dist[k] / TEMP;
            lm = fmaxf(lm, logit[k]);
        }
        float s = 0.f;
        for (int k = 0; k < KC; ++k) { e[k] = expf(logit[k] - lm); s += e[k]; }
        float inv = 1.f / s;
        for (int k = 0; k < KC; ++k) wgt[t * KC + k] = e[k] * inv;
        if (FINAL) {
            float md = dist[0];
            for (int k = 1; k < KC; ++k) md = fminf(md, dist[k]);
            int ca = 0; float best = e[0] * inv;
            for (int k = 1; k < KC; ++k) {
                float wv = e[k] * inv;
                if (wv > best) { best = wv; ca = k; }
            }
            mind[t] = md;
            keys[t] = (float)ca * 1000.0f + (1.0f - best);
        }
    }
}

// ---- FUSED assign + update-pass1 (bit-exact weights; x parked in LDS) ----
__global__ __launch_bounds__(512) void asupd_k(const float* __restrict__ x,
                                               const float* __restrict__ cen0,
                                               int cbstride,
                                               float* __restrict__ part,
                                               float* __restrict__ denp) {
    int blk = blockIdx.x;        // b*SEGU + seg
    int b = blk >> 6, seg = blk & 63;
    constexpr int TSEG = N / SEGU;   // 16
    __shared__ float xs[TSEG][DM];   // 32 KB
    __shared__ float sw[TSEG][KC];
    int tid = threadIdx.x;
    int wv = tid >> 6, lane = tid & 63;
    int n0 = seg * TSEG;
    const float* cenb = cen0 + (size_t)b * cbstride;
#pragma unroll
    for (int half = 0; half < 2; ++half) {
        int tl = wv + half * 8;
        int t = (b << 10) + n0 + tl;
        const float4* xr = (const float4*)(x + (size_t)t * DM);
        float4 xv0 = xr[lane], xv1 = xr[lane + 64];
        ((float4*)&xs[tl][0])[lane] = xv0;
        ((float4*)&xs[tl][0])[lane + 64] = xv1;
        float d2[KC];
#pragma unroll
        for (int k = 0; k < KC; ++k) {
            const float4* cr = (const float4*)(cenb + k * DM);
            float4 c0 = cr[lane], c1 = cr[lane + 64];
            float dx = xv0.x - c0.x, dy = xv0.y - c0.y, dz = xv0.z - c0.z, dw = xv0.w - c0.w;
            float acc = dx * dx + dy * dy + dz * dz + dw * dw;
            dx = xv1.x - c1.x; dy = xv1.y - c1.y; dz = xv1.z - c1.z; dw = xv1.w - c1.w;
            acc += dx * dx + dy * dy + dz * dz + dw * dw;
            d2[k] = acc;
        }
#pragma unroll
        for (int k = 0; k < KC; ++k)
            for (int off = 32; off > 0; off >>= 1) d2[k] += __shfl_xor(d2[k], off);
        if (lane == 0) {
            float logit[KC], e[KC];
            float lm = -1e30f;
            for (int k = 0; k < KC; ++k) {
                float dist = sqrtf(d2[k] + 1e-12f);
                logit[k] = -dist / TEMP;
                lm = fmaxf(lm, logit[k]);
            }
            float s = 0.f;
            for (int k = 0; k < KC; ++k) { e[k] = expf(logit[k] - lm); s += e[k]; }
            float inv = 1.f / s;
            for (int k = 0; k < KC; ++k) sw[tl][k] = e[k] * inv;
        }
    }
    __syncthreads();
    int c = tid;
    float acc[KC] = {};
    for (int n = 0; n < TSEG; ++n) {
        float xv = xs[n][c];
#pragma unroll
        for (int k = 0; k < KC; ++k) acc[k] = fmaf(sw[n][k], xv, acc[k]);
    }
#pragma unroll
    for (int k = 0; k < KC; ++k)
        part[(((size_t)b * KC + k) * SEGU + seg) * DM + c] = acc[k];
    if (c < KC) {
        float dn = 0.f;
        for (int n = 0; n < TSEG; ++n) dn += sw[n][c];
        denp[((size_t)b * KC + c) * SEGU + seg] = dn;
    }
}

// ---- update: pass2 reduce ----
__global__ __launch_bounds__(512) void updr_k(const float* __restrict__ part,
                                              const float* __restrict__ denp,
                                              float* __restrict__ centers) {
    int bk = blockIdx.x;         // 0..B*KC-1
    int c = threadIdx.x;
    const float* pb = part + (size_t)bk * SEGU * DM + c;
    float acc = 0.f;
    for (int g = 0; g < SEGU; ++g) acc += pb[(size_t)g * DM];
    __shared__ float sden;
    if (c == 0) {
        float dn = 0.f;
        const float* db = denp + (size_t)bk * SEGU;
        for (int g = 0; g < SEGU; ++g) dn += db[g];
        sden = dn;
    }
    __syncthreads();
    centers[(size_t)bk * DM + c] = acc / (sden + 1e-8f);
}

// ---- merged sort (blocks 0..3) + importance (blocks 4..7) ----
__global__ __launch_bounds__(1024) void sortimp_k(const float* __restrict__ keys,
                                                  const float* __restrict__ mind,
                                                  int* __restrict__ ridx,
                                                  float* __restrict__ imp) {
    __shared__ unsigned long long a[1024];
    int tid = threadIdx.x;
    if (blockIdx.x < 4) {
        int b = blockIdx.x;
        unsigned int kb = __float_as_uint(keys[b * N + tid]);   // keys >= 0
        a[tid] = ((unsigned long long)kb << 32) | (unsigned int)tid;
        __syncthreads();
        for (int k = 2; k <= 1024; k <<= 1) {
            for (int j = k >> 1; j > 0; j >>= 1) {
                int ixj = tid ^ j;
                if (ixj > tid) {
                    unsigned long long x0 = a[tid], x1 = a[ixj];
                    bool up = ((tid & k) == 0);
                    bool sw = up ? (x0 > x1) : (x0 < x1);
                    if (sw) { a[tid] = x1; a[ixj] = x0; }
                }
                __syncthreads();
            }
        }
        ridx[b * N + tid] = (int)(a[tid] & 0xffffffffu);
    } else {
        int b = blockIdx.x - 4;
        float* red = (float*)a;
        float v = -mind[b * N + tid] / TEMP;
        red[tid] = v; __syncthreads();
        for (int s = 512; s > 0; s >>= 1) { if (tid < s) red[tid] = fmaxf(red[tid], red[tid + s]); __syncthreads(); }
        float m = red[0]; __syncthreads();
        float e = expf(v - m);
        red[tid] = e; __syncthreads();
        for (int s = 512; s > 0; s >>= 1) { if (tid < s) red[tid] += red[tid + s]; __syncthreads(); }
        imp[b * N + tid] = e / red[0];
    }
}

// ---- gather into combined 2-stream activation buffer + combined importance ----
__global__ __launch_bounds__(512) void gather_k(const float* __restrict__ x,
                                                const float* __restrict__ imp,
                                                const int* __restrict__ ridx,
                                                float* __restrict__ act0,
                                                float* __restrict__ impc) {
    int t = blockIdx.x;
    int b = t >> 10, j = t & (N - 1);
    int r = ridx[t];
    int c = threadIdx.x;
    float v = x[((size_t)(b << 10) + r) * DM + c];
    act0[(size_t)t * DM + c] = v;
    act0[((size_t)TT + (b << 10) + (N - 1 - j)) * DM + c] = v;
    if (c == 0) {
        float iv = imp[(b << 10) + r];
        impc[t] = iv;
        impc[TT + (b << 10) + (N - 1 - j)] = iv;
    }
}

// ---------------- merged weight prep ----------------
__device__ inline void tconv_body(const float* __restrict__ src, ushort* __restrict__ dst,
                                  int R, int C, int c0, int r0, float* tile /*32x33*/) {
    int tx = threadIdx.x & 31, ty = threadIdx.x >> 5;
#pragma unroll
    for (int j = 0; j < 4; ++j)
        tile[(ty + j * 8) * 33 + tx] = src[(size_t)(r0 + ty + j * 8) * C + c0 + tx];
    __syncthreads();
#pragma unroll
    for (int j = 0; j < 4; ++j)
        dst[(size_t)(c0 + ty + j * 8) * R + r0 + tx] = f2bf(tile[tx * 33 + ty + j * 8]);
}

__global__ __launch_bounds__(256) void prep_k(const float* __restrict__ in_w,
                                              const float* __restrict__ cm_w2,
                                              const float* __restrict__ out_w,
                                              const float* __restrict__ fusion_w,
                                              const float* __restrict__ xp_w,
                                              ushort* __restrict__ inwT, ushort* __restrict__ cmw2T,
                                              ushort* __restrict__ outwT, ushort* __restrict__ fusT,
                                              ushort* __restrict__ xpwT) {
    __shared__ float lds[256 * 33];
    int bx = blockIdx.x;
    if (bx < 4096) {                       // in_w: 4 layers x (64 x 16)
        int l = bx >> 10, i = bx & 1023;
        tconv_body(in_w + (size_t)l * DM * 2 * DI, inwT + (size_t)l * 2 * DI * DM,
                   DM, 2 * DI, (i & 63) * 32, (i >> 6) * 32, lds);
        return;
    }
    bx -= 4096;
    if (bx < 1024) {                       // cm_w2: 4 x (32 x 8)
        int l = bx >> 8, i = bx & 255;
        tconv_body(cm_w2 + (size_t)l * DI4 * DI, cmw2T + (size_t)l * DI * DI4,
                   DI4, DI, (i & 31) * 32, (i >> 5) * 32, lds);
        return;
    }
    bx -= 1024;
    if (bx < 2048) {                       // out_w: 4 x (16 x 32)
        int l = bx >> 9, i = bx & 511;
        tconv_body(out_w + (size_t)l * DI * DM, outwT + (size_t)l * DM * DI,
                   DI, DM, (i & 15) * 32, (i >> 4) * 32, lds);
        return;
    }
    bx -= 2048;
    if (bx < 512) {                        // fusion: 16 x 32
        tconv_body(fusion_w, fusT, 2 * DM, DM, (bx & 15) * 32, (bx >> 4) * 32, lds);
        return;
    }
    bx -= 512;
    {                                      // xp_w prep: 16 blocks
        int l = bx >> 2, chunk = bx & 3;
        int c0 = chunk * 256, tid = threadIdx.x;
        const float* src = xp_w + (size_t)l * DI * 33 + (size_t)c0 * 33;
        for (int i = tid; i < 256 * 33; i += 256) lds[i] = src[i];
        __syncthreads();
        ushort* dst = xpwT + (size_t)l * 128 * DI;
        for (int j = 0; j < 128; ++j) {
            ushort v = (j < 33) ? f2bf(lds[tid * 33 + j]) : (ushort)0;
            dst[(size_t)j * DI + c0 + tid] = v;
        }
    }
}

// ---------------- xssmP partials [4][TT2][128] -> xssmT [33][TT2] ----------------
__global__ __launch_bounds__(256) void tpose33_k(const float* __restrict__ xssmP,
                                                 float* __restrict__ xssmT) {
    int t0 = blockIdx.x * 64, tid = threadIdx.x;
    __shared__ float lds[64 * 129];
    const float* src = xssmP + (size_t)t0 * 128;
    const size_t PS = (size_t)TT2 * 128;
    for (int i = tid; i < 64 * 128; i += 256) {
        float v = src[i] + src[i + PS] + src[i + 2 * PS] + src[i + 3 * PS];
        lds[(i >> 7) * 129 + (i & 127)] = v;
    }
    __syncthreads();
    int tk = tid & 63, jq = tid >> 6;
    for (int j = jq; j < 33; j += 4)
        xssmT[(size_t)j * TT2 + t0 + tk] = lds[tk * 129 + j];
}

// ---------------- layernorm: wave-per-token over TT2, per-half layer params ----------------
__global__ __launch_bounds__(256) void ln_k(const float* __restrict__ xin,
                                            const float* __restrict__ ln_g,
                                            const float* __restrict__ ln_b,
                                            int lA, int lB,
                                            ushort* __restrict__ out) {
    int t = blockIdx.x * 4 + (threadIdx.x >> 6);
    int lane = threadIdx.x & 63;
    int l = (t < TT) ? lA : lB;
    const float* g = ln_g + (size_t)l * DM;
    const float* bt = ln_b + (size_t)l * DM;
    const float4* xr = (const float4*)(xin + (size_t)t * DM);
    float4 v0 = xr[lane * 2], v1 = xr[lane * 2 + 1];
    float s = ((v0.x + v0.y) + (v0.z + v0.w)) + ((v1.x + v1.y) + (v1.z + v1.w));
#pragma unroll
    for (int off = 32; off > 0; off >>= 1) s += __shfl_xor(s, off);
    float mu = s * (1.f / DM);
    float d0 = v0.x - mu, d1 = v0.y - mu, d2 = v0.z - mu, d3 = v0.w - mu;
    float d4 = v1.x - mu, d5 = v1.y - mu, d6 = v1.z - mu, d7 = v1.w - mu;
    float q = ((d0 * d0 + d1 * d1) + (d2 * d2 + d3 * d3)) + ((d4 * d4 + d5 * d5) + (d6 * d6 + d7 * d7));
#pragma unroll
    for (int off = 32; off > 0; off >>= 1) q += __shfl_xor(q, off);
    float rs = rsqrtf(q * (1.f / DM) + 1e-5f);
    const float4* gr = (const float4*)g;
    const float4* br = (const float4*)bt;
    float4 g0 = gr[lane * 2], g1 = gr[lane * 2 + 1];
    float4 b0 = br[lane * 2], b1 = br[lane * 2 + 1];
    uint4 pk;
    pk.x = (unsigned)f2bf(d0 * rs * g0.x + b0.x) | ((unsigned)f2bf(d1 * rs * g0.y + b0.y) << 16);
    pk.y = (unsigned)f2bf(d2 * rs * g0.z + b0.z) | ((unsigned)f2bf(d3 * rs * g0.w + b0.w) << 16);
    pk.z = (unsigned)f2bf(d4 * rs * g1.x + b1.x) | ((unsigned)f2bf(d5 * rs * g1.y + b1.y) << 16);
    pk.w = (unsigned)f2bf(d6 * rs * g1.z + b1.z) | ((unsigned)f2bf(d7 * rs * g1.w + b1.w) << 16);
    *(uint4*)(out + (size_t)t * DM + lane * 8) = pk;
}

// ---------------- MFMA bf16 GEMM, dbuf gld16; per-row-half B/bias; split-K via gridDim.z ----------------
template <bool BF16OUT>
__global__ __launch_bounds__(256) void mgemm_k(const ushort* __restrict__ A, int lda,
                                               const ushort* __restrict__ BtA,
                                               const ushort* __restrict__ BtB, int ldb,
                                               const float* __restrict__ biasA,
                                               const float* __restrict__ biasB,
                                               const float* __restrict__ add, int ldadd,
                                               void* __restrict__ Cout, int ldc, int Kdim,
                                               size_t czs) {
    __shared__ short8v As[2][128 * 4];
    __shared__ short8v Bs[2][128 * 4];
    int tid = threadIdx.x;
    int lane = tid & 63, wid = tid >> 6;
    int row0 = blockIdx.y * 128, col0 = blockIdx.x * 128;
    const ushort* Bt = (row0 < TT || !BtB) ? BtA : BtB;
    const float* bias = (row0 < TT || !BtB) ? biasA : biasB;
    int wr = (wid >> 1) * 64, wc = (wid & 1) * 64;
    float4v acc[4][4];
#pragma unroll
    for (int i = 0; i < 4; ++i)
#pragma unroll
        for (int j = 0; j < 4; ++j)
#pragma unroll
            for (int r = 0; r < 4; ++r) acc[i][j][r] = 0.f;

    int rq0 = wid * 32 + (lane >> 2);
    int rq1 = rq0 + 16;
    int clds = lane & 3;
    int cs0 = clds ^ ((rq0 >> 1) & 3);
    int cs1 = clds ^ ((rq1 >> 1) & 3);
    const ushort* aSrc0 = A + (size_t)(row0 + rq0) * lda + cs0 * 8;
    const ushort* aSrc1 = A + (size_t)(row0 + rq1) * lda + cs1 * 8;
    const ushort* bSrc0 = Bt + (size_t)(col0 + rq0) * ldb + cs0 * 8;
    const ushort* bSrc1 = Bt + (size_t)(col0 + rq1) * ldb + cs1 * 8;

    int fr = lane & 15, kg = lane >> 4;
    int sf = kg ^ ((fr >> 1) & 3);

    int kslice = Kdim / (int)gridDim.z;
    int kbeg = (int)blockIdx.z * kslice;
    int T = kslice / 32;

    gld16(aSrc0 + kbeg, &As[0][wid * 128]);
    gld16(aSrc1 + kbeg, &As[0][wid * 128 + 64]);
    gld16(bSrc0 + kbeg, &Bs[0][wid * 128]);
    gld16(bSrc1 + kbeg, &Bs[0][wid * 128 + 64]);
    __syncthreads();
    int cur = 0;
    for (int i = 0; i < T; ++i) {
        if (i + 1 < T) {
            int kn = kbeg + (i + 1) * 32;
            gld16(aSrc0 + kn, &As[cur ^ 1][wid * 128]);
            gld16(aSrc1 + kn, &As[cur ^ 1][wid * 128 + 64]);
            gld16(bSrc0 + kn, &Bs[cur ^ 1][wid * 128]);
            gld16(bSrc1 + kn, &Bs[cur ^ 1][wid * 128 + 64]);
        }
        short8v af[4], bf[4];
#pragma unroll
        for (int mb = 0; mb < 4; ++mb) af[mb] = As[cur][(wr + mb * 16 + fr) * 4 + sf];
#pragma unroll
        for (int nb = 0; nb < 4; ++nb) bf[nb] = Bs[cur][(wc + nb * 16 + fr) * 4 + sf];
#pragma unroll
        for (int mb = 0; mb < 4; ++mb)
#pragma unroll
            for (int nb = 0; nb < 4; ++nb)
                acc[mb][nb] = __builtin_amdgcn_mfma_f32_16x16x32_bf16(af[mb], bf[nb], acc[mb][nb], 0, 0, 0);
        __syncthreads();
        cur ^= 1;
    }
    ushort* cu = (ushort*)Cout + (size_t)blockIdx.z * czs;
    float* cf = (float*)Cout + (size_t)blockIdx.z * czs;
#pragma unroll
    for (int mb = 0; mb < 4; ++mb) {
        int r_ = row0 + wr + mb * 16 + kg * 4;
#pragma unroll
        for (int nb = 0; nb < 4; ++nb) {
            int c_ = col0 + wc + nb * 16 + fr;
            float bz = bias ? bias[c_] : 0.f;
#pragma unroll
            for (int r = 0; r < 4; ++r) {
                float o = acc[mb][nb][r] + bz;
                if (add) o += add[(size_t)(r_ + r) * ldadd + c_];
                if (BF16OUT) cu[(size_t)(r_ + r) * ldc + c_] = f2bf(o);
                else         cf[(size_t)(r_ + r) * ldc + c_] = o;
            }
        }
    }
}

// ---------------- h1-fused cm_w2 GEMM, dbuf, per-row-half layer (bf16 modl out) ----------------
__global__ __launch_bounds__(256) void mgemmH_k(const float* __restrict__ impc,
                                                const float* __restrict__ cm_w1,
                                                const float* __restrict__ cm_b1,
                                                const ushort* __restrict__ cmw2T,
                                                const float* __restrict__ cm_b2,
                                                int lA, int lB,
                                                ushort* __restrict__ Cout, int ldc) {
    __shared__ short8v As[2][128 * 4];
    __shared__ short8v Bs[2][128 * 4];
    int tid = threadIdx.x;
    int lane = tid & 63, wid = tid >> 6;
    int row0 = blockIdx.y * 128, col0 = blockIdx.x * 128;
    int l = (row0 < TT) ? lA : lB;
    const float* w1 = cm_w1 + (size_t)l * DI4;
    const float* b1 = cm_b1 + (size_t)l * DI4;
    const ushort* Bt = cmw2T + (size_t)l * DI * DI4;
    const float* bias = cm_b2 + (size_t)l * DI;
    int wr = (wid >> 1) * 64, wc = (wid & 1) * 64;
    float4v acc[4][4];
#pragma unroll
    for (int i = 0; i < 4; ++i)
#pragma unroll
        for (int j = 0; j < 4; ++j)
#pragma unroll
            for (int r = 0; r < 4; ++r) acc[i][j][r] = 0.f;

    int rq0 = wid * 32 + (lane >> 2);
    int rq1 = rq0 + 16;
    int clds = lane & 3;
    int cs0 = clds ^ ((rq0 >> 1) & 3);
    int cs1 = clds ^ ((rq1 >> 1) & 3);
    float imp0 = impc[row0 + rq0];
    float imp1 = impc[row0 + rq1];
    const ushort* bSrc0 = Bt + (size_t)(col0 + rq0) * DI4 + cs0 * 8;
    const ushort* bSrc1 = Bt + (size_t)(col0 + rq1) * DI4 + cs1 * 8;

    int fr = lane & 15, kg = lane >> 4;
    int sf = kg ^ ((fr >> 1) & 3);

    auto mkA = [&](int k0, float impv, int cs, short8v* dst) {
        float4 w0 = *(const float4*)(w1 + k0 + cs * 8);
        float4 w4 = *(const float4*)(w1 + k0 + cs * 8 + 4);
        float4 bq0 = *(const float4*)(b1 + k0 + cs * 8);
        float4 bq4 = *(const float4*)(b1 + k0 + cs * 8 + 4);
        short8v p;
        p[0] = (short)f2bf(fmaxf(fmaf(impv, w0.x, bq0.x), 0.f));
        p[1] = (short)f2bf(fmaxf(fmaf(impv, w0.y, bq0.y), 0.f));
        p[2] = (short)f2bf(fmaxf(fmaf(impv, w0.z, bq0.z), 0.f));
        p[3] = (short)f2bf(fmaxf(fmaf(impv, w0.w, bq0.w), 0.f));
        p[4] = (short)f2bf(fmaxf(fmaf(impv, w4.x, bq4.x), 0.f));
        p[5] = (short)f2bf(fmaxf(fmaf(impv, w4.y, bq4.y), 0.f));
        p[6] = (short)f2bf(fmaxf(fmaf(impv, w4.z, bq4.z), 0.f));
        p[7] = (short)f2bf(fmaxf(fmaf(impv, w4.w, bq4.w), 0.f));
        *dst = p;
    };

    mkA(0, imp0, cs0, &As[0][rq0 * 4 + clds]);
    mkA(0, imp1, cs1, &As[0][rq1 * 4 + clds]);
    gld16(bSrc0, &Bs[0][wid * 128]);
    gld16(bSrc1, &Bs[0][wid * 128 + 64]);
    __syncthreads();
    int cur = 0;
    constexpr int T = DI4 / 32;   // 8
    for (int i = 0; i < T; ++i) {
        if (i + 1 < T) {
            int kn = (i + 1) * 32;
            mkA(kn, imp0, cs0, &As[cur ^ 1][rq0 * 4 + clds]);
            mkA(kn, imp1, cs1, &As[cur ^ 1][rq1 * 4 + clds]);
            gld16(bSrc0 + kn, &Bs[cur ^ 1][wid * 128]);
            gld16(bSrc1 + kn, &Bs[cur ^ 1][wid * 128 + 64]);
        }
        short8v af[4], bf[4];
#pragma unroll
        for (int mb = 0; mb < 4; ++mb) af[mb] = As[cur][(wr + mb * 16 + fr) * 4 + sf];
#pragma unroll
        for (int nb = 0; nb < 4; ++nb) bf[nb] = Bs[cur][(wc + nb * 16 + fr) * 4 + sf];
#pragma unroll
        for (int mb = 0; mb < 4; ++mb)
#pragma unroll
            for (int nb = 0; nb < 4; ++nb)
                acc[mb][nb] = __builtin_amdgcn_mfma_f32_16x16x32_bf16(af[mb], bf[nb], acc[mb][nb], 0, 0, 0);
        __syncthreads();
        cur ^= 1;
    }
#pragma unroll
    for (int mb = 0; mb < 4; ++mb) {
        int r_ = row0 + wr + mb * 16 + kg * 4;
#pragma unroll
        for (int nb = 0; nb < 4; ++nb) {
            int c_ = col0 + wc + nb * 16 + fr;
            float bz = bias[c_];
#pragma unroll
            for (int r = 0; r < 4; ++r)
                Cout[(size_t)(r_ + r) * ldc + c_] = f2bf(acc[mb][nb][r] + bz);
        }
    }
}

// ---------------- depthwise causal conv + silu (ushort2), per-half layer ----------------
__global__ __launch_bounds__(256) void conv_k(const ushort* __restrict__ xz,
                                              const float* __restrict__ conv_w,
                                              const float* __restrict__ conv_b,
                                              int lA, int lB,
                                              ushort* __restrict__ xcb) {
    int gid = blockIdx.x * 256 + threadIdx.x;   // pair index over TT2*DI/2
    int p = gid & (DI / 2 - 1);
    int d = p * 2;
    int t = gid >> 9;
    int n = t & (N - 1);
    int l = (t < TT) ? lA : lB;
    const float* cw = conv_w + (size_t)l * DI * DC;
    const float* cb = conv_b + (size_t)l * DI;
    float acc0 = cb[d], acc1 = cb[d + 1];
    const ushort* base = xz + (size_t)t * (2 * DI) + d;
    float4 w0 = *(const float4*)(cw + d * DC);
    float4 w1 = *(const float4*)(cw + (d + 1) * DC);
    float wk0[4] = {w0.x, w0.y, w0.z, w0.w};
    float wk1[4] = {w1.x, w1.y, w1.z, w1.w};
#pragma unroll
    for (int k = 0; k < DC; ++k) {
        int nn = n - (DC - 1) + k;
        if (nn >= 0) {
            unsigned u = *(const unsigned*)(base + (long)(nn - n) * (2 * DI));
            acc0 = fmaf(bf2f((ushort)(u & 0xffff)), wk0[k], acc0);
            acc1 = fmaf(bf2f((ushort)(u >> 16)), wk1[k], acc1);
        }
    }
    float s0 = acc0 * sigm(acc0);
    float s1 = acc1 * sigm(acc1);
    unsigned o = (unsigned)f2bf(s0) | ((unsigned)f2bf(s1) << 16);
    *(unsigned*)(xcb + (size_t)t * DI + d) = o;
}

// ================= segmented scan (batched: b 0..7, per-half layer) =================
// Phase A: computes delta from modl; local scan + transfer product; writes delf.
__global__ __launch_bounds__(256) void scanA_k(const ushort* __restrict__ modl,
                                               const ushort* __restrict__ xcb,
                                               const float* __restrict__ xssmT,
                                               const float* __restrict__ Alog0,
                                               const float* __restrict__ dtw0,
                                               const float* __restrict__ dtb0,
                                               int lA, int lB,
                                               float* __restrict__ delf,
                                               float* __restrict__ hloc,
                                               float* __restrict__ Pp) {
    int blk = blockIdx.x;
    int seg = blk & 15;
    int dblk = (blk >> 4) & 63;
    int b = blk >> 10;                 // 0..7
    int l = (b < 4) ? lA : lB;
    const float* Alog = Alog0 + (size_t)l * DI * DS;
    const float* dtw = dtw0 + (size_t)l * DI;
    const float* dtb = dtb0 + (size_t)l * DI;
    int d0 = dblk * 16;
    int tid = threadIdx.x;
    int lane = tid & 63, wave = tid >> 6;
    int s = lane & 15, dd = lane >> 4;
    int dl = wave * 4 + dd, d = d0 + dl;
    float A2 = -__expf(Alog[d * DS + s]) * LOG2E;
    size_t tokbase = (size_t)b * N + (size_t)seg * SLEN;

    __shared__ float sdl[16][68];
    __shared__ float sxc[16][68];
    __shared__ float sBv[16][68];

    int lc = tid & 15, lr = tid >> 4;
    float dtwv = dtw[d0 + lc], dtbv = dtb[d0 + lc];
    const ushort* mbase = modl + tokbase * DI + d0 + lc;
    const ushort* xbase = xcb + tokbase * DI + d0 + lc;
    const float* drow = xssmT + tokbase;
    const float* Brow = xssmT + (size_t)(1 + lc) * TT2 + tokbase;
#pragma unroll
    for (int q = 0; q < 4; ++q) {
        int tok = q * 16 + lr;
        float mo   = bf2f(mbase[(size_t)tok * DI]);
        float draw = drow[tok];
        float xcv  = bf2f(xbase[(size_t)tok * DI]);
        float Bv   = Brow[tok];
        float a = draw * dtwv + dtbv;
        float sp = softp(a);
        float mod = sigm(mo);
        float dlv = sp * (1.f + mod);
        sdl[lc][tok] = dlv;
        delf[(tokbase + tok) * DI + d0 + lc] = dlv;
        sxc[lc][tok] = xcv;
        sBv[lc][tok] = Bv;
    }
    __syncthreads();
    float h = 0.f, P = 1.f;
#pragma unroll
    for (int g = 0; g < 8; ++g) {
        float4 dl4a = *(const float4*)&sdl[dl][g * 8];
        float4 dl4b = *(const float4*)&sdl[dl][g * 8 + 4];
        float4 xc4a = *(const float4*)&sxc[dl][g * 8];
        float4 xc4b = *(const float4*)&sxc[dl][g * 8 + 4];
        float4 B4a  = *(const float4*)&sBv[s][g * 8];
        float4 B4b  = *(const float4*)&sBv[s][g * 8 + 4];
        float dlt[8] = {dl4a.x, dl4a.y, dl4a.z, dl4a.w, dl4b.x, dl4b.y, dl4b.z, dl4b.w};
        float xcv[8] = {xc4a.x, xc4a.y, xc4a.z, xc4a.w, xc4b.x, xc4b.y, xc4b.z, xc4b.w};
        float Bv8[8] = {B4a.x, B4a.y, B4a.z, B4a.w, B4b.x, B4b.y, B4b.z, B4b.w};
        float a8[8], b8[8];
#pragma unroll
        for (int j = 0; j < 8; ++j) {
            a8[j] = hexp2(dlt[j] * A2);
            b8[j] = (dlt[j] * Bv8[j]) * xcv[j];
        }
#pragma unroll
        for (int j = 0; j < 8; ++j) { h = fmaf(a8[j], h, b8[j]); P *= a8[j]; }
    }
    size_t idx = (size_t)blk * 256 + tid;
    hloc[idx] = h;
    Pp[idx] = P;
}

__global__ __launch_bounds__(256) void scanB_k(const float* __restrict__ hloc,
                                               const float* __restrict__ Pp,
                                               float* __restrict__ h0g) {
    int blk = blockIdx.x;     // 0..511 (8*64)
    int tid = threadIdx.x;
    size_t base = (size_t)blk * SEG * 256 + tid;
    float h = 0.f;
    for (int g = 0; g < SEG; ++g) {
        size_t i = base + (size_t)g * 256;
        h0g[i] = h;
        h = fmaf(Pp[i], h, hloc[i]);
    }
}

// Phase C: re-run segment from true h0; 16-token sP groups, scalar reduce (R12 config).
__global__ __launch_bounds__(256) void scanC_k(const float* __restrict__ delf,
                                               const ushort* __restrict__ xcb,
                                               const float* __restrict__ xssmT,
                                               const float* __restrict__ Alog0,
                                               const float* __restrict__ Dp0,
                                               const ushort* __restrict__ xz,
                                               int lA, int lB,
                                               const float* __restrict__ h0g,
                                               ushort* __restrict__ y) {
    int blk = blockIdx.x;
    int seg = blk & 15;
    int dblk = (blk >> 4) & 63;
    int b = blk >> 10;                 // 0..7
    int l = (b < 4) ? lA : lB;
    const float* Alog = Alog0 + (size_t)l * DI * DS;
    const float* Dp = Dp0 + (size_t)l * DI;
    int d0 = dblk * 16;
    int tid = threadIdx.x;
    int lane = tid & 63, wave = tid >> 6;
    int s = lane & 15, dd = lane >> 4;
    int dl = wave * 4 + dd, d = d0 + dl;
    float A2 = -__expf(Alog[d * DS + s]) * LOG2E;
    size_t tokbase = (size_t)b * N + (size_t)seg * SLEN;

    __shared__ float sdl[16][68];
    __shared__ float sxc[16][68];
    __shared__ float sBv[16][68];
    __shared__ float sCv[16][68];
    __shared__ float szv[16][68];
    __shared__ float sP[16][16][17];

    int lc = tid & 15, lr = tid >> 4;
    float dpv_lc = Dp[d0 + lc];
    const float* dbase = delf + tokbase * DI + d0 + lc;
    const ushort* xbase = xcb + tokbase * DI + d0 + lc;
    const ushort* zbase = xz + tokbase * (2 * DI) + DI + d0 + lc;
    const float* Brow = xssmT + (size_t)(1 + lc) * TT2 + tokbase;
    const float* Crow = xssmT + (size_t)(1 + DS + lc) * TT2 + tokbase;
#pragma unroll
    for (int q = 0; q < 4; ++q) {
        int tok = q * 16 + lr;
        sdl[lc][tok] = dbase[(size_t)tok * DI];
        sxc[lc][tok] = bf2f(xbase[(size_t)tok * DI]);
        sBv[lc][tok] = Brow[tok];
        sCv[lc][tok] = Crow[tok];
        szv[lc][tok] = bf2f(zbase[(size_t)tok * (2 * DI)]);
    }
    __syncthreads();
    float h = h0g[(size_t)blk * 256 + tid];
    for (int g = 0; g < 4; ++g) {              // 16-token groups
#pragma unroll
        for (int half = 0; half < 2; ++half) {
            int t0 = g * 16 + half * 8;
            float4 dl4a = *(const float4*)&sdl[dl][t0];
            float4 dl4b = *(const float4*)&sdl[dl][t0 + 4];
            float4 xc4a = *(const float4*)&sxc[dl][t0];
            float4 xc4b = *(const float4*)&sxc[dl][t0 + 4];
            float4 B4a  = *(const float4*)&sBv[s][t0];
            float4 B4b  = *(const float4*)&sBv[s][t0 + 4];
            float4 C4a  = *(const float4*)&sCv[s][t0];
            float4 C4b  = *(const float4*)&sCv[s][t0 + 4];
            float dlt[8] = {dl4a.x, dl4a.y, dl4a.z, dl4a.w, dl4b.x, dl4b.y, dl4b.z, dl4b.w};
            float xcv[8] = {xc4a.x, xc4a.y, xc4a.z, xc4a.w, xc4b.x, xc4b.y, xc4b.z, xc4b.w};
            float Bv8[8] = {B4a.x, B4a.y, B4a.z, B4a.w, B4b.x, B4b.y, B4b.z, B4b.w};
            float Cv8[8] = {C4a.x, C4a.y, C4a.z, C4a.w, C4b.x, C4b.y, C4b.z, C4b.w};
            float a8[8], b8[8];
#pragma unroll
            for (int j = 0; j < 8; ++j) {
                a8[j] = hexp2(dlt[j] * A2);
                b8[j] = (dlt[j] * Bv8[j]) * xcv[j];
            }
#pragma unroll
            for (int j = 0; j < 8; ++j) {
                h = fmaf(a8[j], h, b8[j]);
                sP[half * 8 + j][dl][s] = h * Cv8[j];
            }
        }
        __syncthreads();
        {
            int t = g * 16 + lr;
            float ssum = 0.f;
#pragma unroll
            for (int s2 = 0; s2 < 16; ++s2) ssum += sP[lr][lc][s2];
            float xcv = sxc[lc][t];
            float zv  = szv[lc][t];
            float sg = sigm(zv);
            y[(tokbase + t) * DI + d0 + lc] = f2bf((ssum + xcv * dpv_lc) * (zv * sg));
        }
        __syncthreads();
    }
}

// ---------------- concat [xf | flip(xb)] from combined act0 -> bf16 ----------------
__global__ __launch_bounds__(256) void concat_k(const float* __restrict__ act0,
                                                ushort* __restrict__ cat) {
    int gid = blockIdx.x * 256 + threadIdx.x;   // TT*DM
    int t = gid >> 9;
    int c = gid & (DM - 1);
    int b = t >> 10, j = t & (N - 1);
    cat[(size_t)t * (2 * DM) + c] = f2bf(act0[(size_t)t * DM + c]);
    cat[(size_t)t * (2 * DM) + DM + c] =
        f2bf(act0[((size_t)TT + (b << 10) + (N - 1 - j)) * DM + c]);
}

// ---------------- final: scatter by ridx + layernorm ----------------
__global__ __launch_bounds__(256) void final_k(const float* __restrict__ fus,
                                               const int* __restrict__ ridx,
                                               const float* __restrict__ g,
                                               const float* __restrict__ bt,
                                               float* __restrict__ out) {
    int t = blockIdx.x, tid = threadIdx.x;
    int b = t >> 10;
    int r = ridx[t];
    const float* xr = fus + (size_t)t * DM;
    __shared__ float red[256];
    float v0 = xr[tid], v1 = xr[tid + 256];
    red[tid] = v0 + v1; __syncthreads();
    for (int st = 128; st > 0; st >>= 1) { if (tid < st) red[tid] += red[tid + st]; __syncthreads(); }
    float mu = red[0] * (1.f / DM); __syncthreads();
    float d0 = v0 - mu, d1 = v1 - mu;
    red[tid] = d0 * d0 + d1 * d1; __syncthreads();
    for (int st = 128; st > 0; st >>= 1) { if (tid < st) red[tid] += red[tid + st]; __syncthreads(); }
    float rs = rsqrtf(red[0] * (1.f / DM) + 1e-5f);
    float* orow = out + ((size_t)(b << 10) + r) * DM;
    orow[tid] = d0 * rs * g[tid] + bt[tid];
    orow[tid + 256] = d1 * rs * g[tid + 256] + bt[tid + 256];
}

// ---------------- host ----------------
extern "C" void kernel_launch(void* const* d_in, const int* in_sizes, int n_in,
                              void* d_out, int out_size, void* d_ws, size_t ws_size,
                              hipStream_t stream) {
    const float* x            = (const float*)d_in[0];
    const float* centers_init = (const float*)d_in[1];
    const float* in_w         = (const float*)d_in[2];
    const float* conv_w       = (const float*)d_in[3];
    const float* conv_b       = (const float*)d_in[4];
    const float* xp_w         = (const float*)d_in[5];
    const float* dt_w         = (const float*)d_in[6];
    const float* dt_b         = (const float*)d_in[7];
    const float* cm_w1        = (const float*)d_in[8];
    const float* cm_b1        = (const float*)d_in[9];
    const float* cm_w2        = (const float*)d_in[10];
    const float* cm_b2        = (const float*)d_in[11];
    const float* A_log        = (const float*)d_in[12];
    const float* D_p          = (const float*)d_in[13];
    const float* out_w        = (const float*)d_in[14];
    const float* ln_g         = (const float*)d_in[15];
    const float* ln_b         = (const float*)d_in[16];
    const float* fusion_w     = (const float*)d_in[17];
    const float* fusion_b     = (const float*)d_in[18];
    const float* fn_g         = (const float*)d_in[19];
    const float* fn_b         = (const float*)d_in[20];

    float* W = (float*)d_ws;
    size_t off = 0;
    auto alloc = [&](size_t n) { float* p = W + off; off += (n + 15) & ~(size_t)15; return p; };
    auto allocU = [&](size_t n) { ushort* p = (ushort*)(W + off); off += ((n + 1) / 2 + 15) & ~(size_t)15; return p; };
    float* centers = alloc((size_t)Bb * KC * DM);
    float* wgt     = alloc((size_t)TT * KC);
    float* mind    = alloc(TT);
    float* keys    = alloc(TT);
    float* imp     = alloc(TT);
    float* impc    = alloc(TT2);
    float* denp    = alloc((size_t)Bb * KC * SEGU);
    float* act0    = alloc((size_t)TT2 * DM);      // combined fwd|bwd activations
    float* act1    = alloc((size_t)TT2 * DM);      // pair intermediate; aliased as fus
    float* xssmT   = alloc((size_t)TT2 * 33);
    float* delf    = alloc((size_t)TT2 * DI);      // f32 delta (scanA -> scanC); aliases kmeans part
    float* hloc    = alloc((size_t)8 * 64 * SEG * 256);   // hloc+Pp aliased by xssmP (16MB)
    float* Pp      = alloc((size_t)8 * 64 * SEG * 256);
    float* h0g     = alloc((size_t)8 * 64 * SEG * 256);
    ushort* xz     = allocU((size_t)TT2 * 2 * DI); // bf16 xz; reused as bf16 cat
    ushort* modl   = allocU((size_t)TT2 * DI);
    ushort* yb     = allocU((size_t)TT2 * DI);     // scanC out; aliased as xnb (disjoint)
    ushort* xcb    = allocU((size_t)TT2 * DI);
    ushort* inwT   = allocU((size_t)L4 * 2 * DI * DM);
    ushort* cmw2T  = allocU((size_t)L4 * DI * DI4);
    ushort* outwT  = allocU((size_t)L4 * DM * DI);
    ushort* fusT   = allocU((size_t)DM * 2 * DM);
    ushort* xpwT   = allocU((size_t)L4 * 128 * DI);
    int* ridx = (int*)(W + off); off += TT;
    float* part = delf;           // kmeans partials alias delf (disjoint in time)
    float* xssmP = hloc;          // 4 split-K partials (16MB) alias hloc+Pp, disjoint in time
    ushort* xnb = yb;             // ln out aliases yb (live ranges disjoint within a pair)
    float* fus = act1;            // fusion out aliases act1 (dead after pair 1)

    // ---- merged weight prep ----
    prep_k<<<7696, 256, 0, stream>>>(in_w, cm_w2, out_w, fusion_w, xp_w,
                                     inwT, cmw2T, outwT, fusT, xpwT);

    // ---- k-means (fused assign+updp per iteration) ----
    for (int it = 0; it < 3; ++it) {
        if (it == 0) asupd_k<<<Bb * SEGU, 512, 0, stream>>>(x, centers_init, 0, part, denp);
        else         asupd_k<<<Bb * SEGU, 512, 0, stream>>>(x, centers, KC * DM, part, denp);
        updr_k<<<Bb * KC, 512, 0, stream>>>(part, denp, centers);
    }
    assign_k<true><<<TT / 4, 256, 0, stream>>>(x, centers, KC * DM, wgt, mind, keys);
    sortimp_k<<<8, 1024, 0, stream>>>(keys, mind, ridx, imp);
    gather_k<<<TT, 512, 0, stream>>>(x, imp, ridx, act0, impc);

    // ---- 2 layer-pairs, each batching fwd (rows 0..TT) and bwd (rows TT..TT2) ----
    float* pin[2]  = {act0, act1};
    float* pout[2] = {act1, act0};
    for (int pr = 0; pr < 2; ++pr) {
        int lA = pr, lB = pr + 2;
        float* actin = pin[pr];
        float* actout = pout[pr];
        ln_k<<<TT2 / 4, 256, 0, stream>>>(actin, ln_g, ln_b, lA, lB, xnb);
        {   // in_w GEMM: M=TT2, N=2048, K=512, bf16 out
            dim3 g(2 * DI / 128, TT2 / 128, 1);
            mgemm_k<true><<<g, 256, 0, stream>>>(xnb, DM,
                inwT + (size_t)lA * 2 * DI * DM, inwT + (size_t)lB * 2 * DI * DM, DM,
                nullptr, nullptr, nullptr, 0, xz, 2 * DI, DM, 0);
        }
        conv_k<<<(TT2 * DI / 2) / 256, 256, 0, stream>>>(xz, conv_w, conv_b, lA, lB, xcb);
        {   // xssm GEMM: split-K=4
            dim3 g(1, TT2 / 128, 4);
            mgemm_k<false><<<g, 256, 0, stream>>>(xcb, DI,
                xpwT + (size_t)lA * 128 * DI, xpwT + (size_t)lB * 128 * DI, DI,
                nullptr, nullptr, nullptr, 0, xssmP, 128, DI, (size_t)TT2 * 128);
        }
        tpose33_k<<<TT2 / 64, 256, 0, stream>>>(xssmP, xssmT);
        mgemmH_k<<<dim3(DI / 128, TT2 / 128), 256, 0, stream>>>(impc, cm_w1, cm_b1, cmw2T, cm_b2,
                                                                lA, lB, modl, DI);
        scanA_k<<<8 * 64 * SEG, 256, 0, stream>>>(modl, xcb, xssmT, A_log, dt_w, dt_b,
                                                  lA, lB, delf, hloc, Pp);
        scanB_k<<<8 * 64, 256, 0, stream>>>(hloc, Pp, h0g);
        scanC_k<<<8 * 64 * SEG, 256, 0, stream>>>(delf, xcb, xssmT, A_log, D_p, xz,
                                                  lA, lB, h0g, yb);
        {   // out_w GEMM: M=TT2, N=512, K=1024, +residual
            dim3 g(DM / 128, TT2 / 128, 1);
            mgemm_k<false><<<g, 256, 0, stream>>>(yb, DI,
                outwT + (size_t)lA * DM * DI, outwT + (size_t)lB * DM * DI, DI,
                nullptr, nullptr, actin, DM, actout, DM, DI, 0);
        }
    }

    // ---- fusion + restore + final LN ----
    ushort* catb = xz;
    concat_k<<<(TT * DM) / 256, 256, 0, stream>>>(act0, catb);
    {
        dim3 g(DM / 128, TT / 128, 1);
        mgemm_k<false><<<g, 256, 0, stream>>>(catb, 2 * DM, fusT, nullptr, 2 * DM,
                                              fusion_b, nullptr, nullptr, 0, fus, DM, 2 * DM, 0);
    }
    final_k<<<TT, 256, 0, stream>>>(fus, ridx, fn_g, fn_b, (float*)d_out);
}